// Round 1
// 60.183 us; speedup vs baseline: 1.0305x; 1.0305x over previous
//
#include <hip/hip_runtime.h>
#include <math.h>

// ANFIS model, collapsed analytically (verified rounds 1 & 3, absmax 9e-13):
//   All MEM_INDEX rows share leading base-3 digit d = r // 2187, and
//   w[j,b] == F0[b]/S for all j (J_LAST=2 -> digit 0). Hence
//     out[b] = F0[b]/S * ( sum_v input[v,b]*Sv[v] + Sv[8] )
//   with Sv[v] = sum_j conseq[9j+v] (j<6561), S = 2187 * sum_b (F0+F1+F2)[b],
//   F_d[b] = 1 / prod_{i=0..7} (1 + (((x_i-c)/a)^2)^bexp)  over rows k=3i+d.
//
// Timed-graph budget (rocprof, this session): 40.2 us harness d_ws poison fill
// (256 MiB @ 83% HBM peak — untouchable floor) + ~15 us harness reset micro-
// dispatches + ~5 us our kernels. This round: k2's Sv gather was 8 dependent
// L3-latency rounds with 9/256 lanes active (~1.8 us); replaced with one
// coalesced 576-wide burst -> LDS -> 9-lane stride-9 (bank-conflict-free) sum,
// and per-batch input/F0 loads hoisted above the reductions to hide latency.

#define NVAR 8
#define TOTALJ 6561
#define NB 2048
#define K1_BLOCKS 64
#define K1_THREADS 256
#define K2_BLOCKS 8
#define K2_THREADS 256

// ws layout (floats):
//   [0,   576)  SvPart[block][9]   (layout [g][v] so k2's LDS-sum is conflict-free)
//   [576, 640)  SsumPart[block]
//   [640, 2688) F0[b]
#define WS_SV    0
#define WS_SSUM  576
#define WS_F0    640

__device__ __forceinline__ float fast_rcp(float x)  { return __builtin_amdgcn_rcpf(x); }
__device__ __forceinline__ float fast_exp2(float x) { return __builtin_amdgcn_exp2f(x); }
__device__ __forceinline__ float fast_log2(float x) { return __builtin_amdgcn_logf(x); }

__global__ __launch_bounds__(K1_THREADS) void anfis_k1(
    const float* __restrict__ input,     // (8, 2048)
    const float* __restrict__ premise,   // (24, 3) rows [a, b, c]
    const float* __restrict__ conseq,    // (59049,)
    float* __restrict__ ws)
{
    const int t    = threadIdx.x;
    const int g    = blockIdx.x;
    const int gt   = g * K1_THREADS + t;
    const int wave = t >> 6;
    const int lane = t & 63;

    // ---- Part A: Sv partial sums (one conseq row of 9 per thread) ----
    float sv[9];
    #pragma unroll
    for (int v = 0; v < 9; ++v) sv[v] = 0.0f;
    if (gt < TOTALJ) {
        const float* row = conseq + gt * 9;
        #pragma unroll
        for (int v = 0; v < 9; ++v) sv[v] = row[v];
    }
    #pragma unroll
    for (int v = 0; v < 9; ++v) {
        #pragma unroll
        for (int m = 32; m; m >>= 1) sv[v] += __shfl_xor(sv[v], m);
    }
    __shared__ float s_sv[4][9];
    if (lane == 0) {
        #pragma unroll
        for (int v = 0; v < 9; ++v) s_sv[wave][v] = sv[v];
    }

    // ---- Part B: membership + F0 per batch (8 lanes per batch) ----
    const int i  = t & 7;          // variable index 0..7
    const int bl = t >> 3;         // local batch 0..31
    const int b  = g * 32 + bl;

    const float x = input[i * NB + b];
    float m3[3];
    #pragma unroll
    for (int d = 0; d < 3; ++d) {
        const int k = 3 * i + d;
        const float pa = premise[k * 3 + 0];
        const float pb = premise[k * 3 + 1];
        const float pc = premise[k * 3 + 2];
        const float tt = (x - pc) * fast_rcp(pa);
        // (tt^2)^b == exp2(2b * log2|tt|); log2(0)=-inf -> exp2(-inf)=0, matches powf
        const float y = fast_exp2(2.0f * pb * fast_log2(__builtin_fabsf(tt)));
        m3[d] = fast_rcp(1.0f + y);
    }
    // product across the 8 lanes of this batch's group (groups are lane-aligned)
    #pragma unroll
    for (int d = 0; d < 3; ++d) {
        m3[d] *= __shfl_xor(m3[d], 1);
        m3[d] *= __shfl_xor(m3[d], 2);
        m3[d] *= __shfl_xor(m3[d], 4);
    }
    if (i == 0) ws[WS_F0 + b] = m3[0];

    float contrib = (i == 0) ? (m3[0] + m3[1] + m3[2]) : 0.0f;
    #pragma unroll
    for (int m = 32; m; m >>= 1) contrib += __shfl_xor(contrib, m);
    __shared__ float s_c[4];
    if (lane == 0) s_c[wave] = contrib;

    __syncthreads();
    if (t < 9) {
        ws[WS_SV + g * 9 + t] = s_sv[0][t] + s_sv[1][t] + s_sv[2][t] + s_sv[3][t];
    }
    if (t == 9) {
        ws[WS_SSUM + g] = s_c[0] + s_c[1] + s_c[2] + s_c[3];
    }
}

__global__ __launch_bounds__(K2_THREADS) void anfis_k2(
    const float* __restrict__ input,
    const float* __restrict__ ws,
    float* __restrict__ out)
{
    __shared__ float s_part[K1_BLOCKS * 9];   // 576
    __shared__ float s_Sv[9];
    __shared__ float s_invS;
    const int t = threadIdx.x;
    const int b = blockIdx.x * K2_THREADS + t;

    // Per-batch loads issued FIRST (independent of the reductions) so their
    // HBM/L3 latency hides under the gather below.
    float xv[NVAR];
    #pragma unroll
    for (int v = 0; v < NVAR; ++v) xv[v] = input[v * NB + b];
    const float f0 = ws[WS_F0 + b];

    // Coalesced one-round gather of all 576 Sv partials (MLP=3 per thread).
    s_part[t]       = ws[WS_SV + t];
    s_part[256 + t] = ws[WS_SV + 256 + t];
    if (t < 64) s_part[512 + t] = ws[WS_SV + 512 + t];

    // S reduction on wave 1, concurrent with the gather above.
    if (t >= 64 && t < 128) {
        float s = ws[WS_SSUM + (t - 64)];
        #pragma unroll
        for (int m = 32; m; m >>= 1) s += __shfl_xor(s, m);
        if (t == 64) s_invS = 1.0f / (2187.0f * s);
    }
    __syncthreads();

    // 9-lane LDS sum, stride 9 floats -> 9 distinct banks, conflict-free.
    if (t < 9) {
        float s = 0.0f;
        #pragma unroll
        for (int g = 0; g < K1_BLOCKS; ++g) s += s_part[g * 9 + t];
        s_Sv[t] = s;
    }
    __syncthreads();

    float D = s_Sv[8];
    #pragma unroll
    for (int v = 0; v < NVAR; ++v) D += xv[v] * s_Sv[v];
    out[b] = f0 * D * s_invS;
}

extern "C" void kernel_launch(void* const* d_in, const int* in_sizes, int n_in,
                              void* d_out, int out_size, void* d_ws, size_t ws_size,
                              hipStream_t stream) {
    const float* input   = (const float*)d_in[0];   // 8*2048
    const float* premise = (const float*)d_in[1];   // 24*3
    const float* conseq  = (const float*)d_in[2];   // 59049
    float* out = (float*)d_out;                     // 2048
    float* ws  = (float*)d_ws;

    anfis_k1<<<K1_BLOCKS, K1_THREADS, 0, stream>>>(input, premise, conseq, ws);
    anfis_k2<<<K2_BLOCKS, K2_THREADS, 0, stream>>>(input, ws, out);
}